// Round 4
// baseline (2604112.109 us; speedup 1.0000x reference)
//
#include <hip/hip_runtime.h>

#define SEQ  512
#define IDIM 256
#define H    1024
#define NC   128
#define B    256
#define NBLK 256

typedef __attribute__((ext_vector_type(8))) short bh8;
typedef __attribute__((ext_vector_type(4))) float f4;
typedef __attribute__((ext_vector_type(4))) int i4;

__device__ __forceinline__ float sigf(float x) { return 1.0f / (1.0f + __expf(-x)); }

__device__ __forceinline__ unsigned short bf16r(float v) {
    unsigned u = __builtin_bit_cast(unsigned, v);
    u += 0x7fffu + ((u >> 16) & 1u);
    return (unsigned short)(u >> 16);
}

// sc0 load: bypass L1, served by (XCD-local) L2 — fresh after same-XCD writers' write-through
__device__ __forceinline__ int load_sc0(const int* p) {
    int v;
    asm volatile("global_load_dword %0, %1, off sc0\n\ts_waitcnt vmcnt(0)"
                 : "=v"(v) : "v"(p) : "memory");
    return v;
}

// ---------------- token tables: FF/II/OO = emb@W*x.T + b*, G = sigmoid(emb@Wcx.T + bc) ----
__global__ __launch_bounds__(256) void tables_kernel(
    const float* __restrict__ emb,
    const float* __restrict__ Wcx, const float* __restrict__ bc,
    const float* __restrict__ Wix, const float* __restrict__ bi,
    const float* __restrict__ Wfx, const float* __restrict__ bf,
    const float* __restrict__ Wox, const float* __restrict__ bo,
    float* __restrict__ FF, float* __restrict__ II,
    float* __restrict__ OO, float* __restrict__ G)
{
    const int k = blockIdx.x;
    const int h = blockIdx.y * 256 + threadIdx.x;
    __shared__ float e[IDIM];
    e[threadIdx.x] = emb[k * IDIM + threadIdx.x];
    __syncthreads();
    const float4* e4  = (const float4*)e;
    const float4* wf4 = (const float4*)(Wfx + (size_t)h * IDIM);
    const float4* wi4 = (const float4*)(Wix + (size_t)h * IDIM);
    const float4* wo4 = (const float4*)(Wox + (size_t)h * IDIM);
    const float4* wc4 = (const float4*)(Wcx + (size_t)h * IDIM);
    float aF = 0.f, aI = 0.f, aO = 0.f, aC = 0.f;
#pragma unroll 4
    for (int i = 0; i < IDIM / 4; i++) {
        float4 ev = e4[i];
        float4 a = wf4[i]; aF += ev.x * a.x + ev.y * a.y + ev.z * a.z + ev.w * a.w;
        float4 b = wi4[i]; aI += ev.x * b.x + ev.y * b.y + ev.z * b.z + ev.w * b.w;
        float4 c = wo4[i]; aO += ev.x * c.x + ev.y * c.y + ev.z * c.z + ev.w * c.w;
        float4 d = wc4[i]; aC += ev.x * d.x + ev.y * d.y + ev.z * d.z + ev.w * d.w;
    }
    const int o = k * H + h;
    FF[o] = aF + bf[h];
    II[o] = aI + bi[h];
    OO[o] = aO + bo[h];
    G[o]  = sigf(aC + bc[h]);
}

// ---------------- weight fp32 -> bf16 swizzled for MFMA B-fragments -----------------------
__global__ __launch_bounds__(256) void swz_kernel(const float* __restrict__ W,
                                                  unsigned short* __restrict__ D)
{
    int g = blockIdx.x * 256 + threadIdx.x;     // 0..131071
    int h  = g >> 7;
    int kc = (g & 127) << 3;
    const float4* s = (const float4*)(W + (size_t)h * H + kc);
    float4 a = s[0], b = s[1];
    unsigned short tmp[8] = { bf16r(a.x), bf16r(a.y), bf16r(a.z), bf16r(a.w),
                              bf16r(b.x), bf16r(b.y), bf16r(b.z), bf16r(b.w) };
    int nb = h >> 4, kb = kc >> 5, quad = (kc >> 3) & 3;
    int lane = (h & 15) + (quad << 4);
    bh8 v;
#pragma unroll
    for (int j = 0; j < 8; j++) v[j] = (short)tmp[j];
    *(bh8*)(D + (size_t)((nb * 32 + kb) * 512 + lane * 8)) = v;
}

// ---------------- persistent recurrence kernel, XCD-local exchange ------------------------
__global__ __launch_bounds__(256, 1) void persist_kernel(
    const unsigned short* __restrict__ Wf, const unsigned short* __restrict__ Wi,
    const unsigned short* __restrict__ Wo,
    const float* __restrict__ FF, const float* __restrict__ II,
    const float* __restrict__ OO, const float* __restrict__ G,
    const int* __restrict__ x,
    unsigned short* c16a, unsigned short* c16b,
    float* __restrict__ hb, int* cnt, int* arr)
{
    const int tid  = threadIdx.x;
    const int wave = tid >> 6;
    const int lane = tid & 63;
    const int msub = wave & 1, nsub = wave >> 1;
    const int l15 = lane & 15, quad = lane >> 4;

    __shared__ unsigned short cs[32 * 1024];   // 64 KB, XOR-swizzled 16B granules
    __shared__ int slot_sh;

    // physical XCD id (0..7) — group by actual placement, not blockIdx
    int xcd;
    asm("s_getreg_b32 %0, hwreg(HW_REG_XCC_ID)" : "=s"(xcd));
    xcd &= 7;
    if (tid == 0)
        slot_sh = __hip_atomic_fetch_add(&cnt[xcd * 32], 1, __ATOMIC_RELAXED,
                                         __HIP_MEMORY_SCOPE_AGENT);
    __syncthreads();
    const int slot = slot_sh;                  // 0..31 within this XCD's group

    const int row0 = xcd * 32;                 // group owns 32 batch rows (XCD-local)
    const int arow = msub * 16 + l15;
    const int abase = arow * 1024;
    const int asw = arow & 7;
    const int hcol = slot * 32 + nsub * 16 + l15;
    const int nb = slot * 2 + nsub;
    int* const barp = &arr[xcd * 32];

    const unsigned short* wfp = Wf + (size_t)nb * 32 * 512 + (size_t)lane * 8;
    const unsigned short* wip = Wi + (size_t)nb * 32 * 512 + (size_t)lane * 8;
    const unsigned short* wop = Wo + (size_t)nb * 32 * 512 + (size_t)lane * 8;

    float cn_keep[4] = {0.f, 0.f, 0.f, 0.f};   // fp32 cell state in registers

    for (int s = 0; s < SEQ; s++) {
        const unsigned short* cur16 = (s & 1) ? c16b : c16a;
        unsigned short*       nxt16 = (s & 1) ? c16a : c16b;

        // token-table prefetch (plain loads; read-only data)
        float ffv[4], iiv[4], ggv[4];
#pragma unroll
        for (int r = 0; r < 4; r++) {
            int b = row0 + msub * 16 + quad * 4 + r;
            int tok = x[b * SEQ + s];
            ffv[r] = FF[tok * H + hcol];
            iiv[r] = II[tok * H + hcol];
            ggv[r] = G[tok * H + hcol];
        }

        f4 accF = {0.f, 0.f, 0.f, 0.f}, accI = {0.f, 0.f, 0.f, 0.f};
        if (s > 0) {
            // stage 32 rows x 2 KB of c from XCD-local L2 (sc0 = L1-bypass), 16 B/lane x16
            i4 tmp[16];
#pragma unroll
            for (int i = 0; i < 16; i++) {
                int chunk = i * 256 + tid;
                int row = chunk >> 7, g = chunk & 127;
                const i4* p = (const i4*)(cur16 + (size_t)(row0 + row) * H + g * 8);
                asm volatile("global_load_dwordx4 %0, %1, off sc0"
                             : "=v"(tmp[i]) : "v"(p));
            }
            asm volatile("s_waitcnt vmcnt(0)" ::: "memory");
#pragma unroll
            for (int i = 0; i < 16; i++) {
                int chunk = i * 256 + tid;
                int row = chunk >> 7, g = chunk & 127;
                *(i4*)(cs + row * 1024 + ((g ^ (row & 7)) << 3)) = tmp[i];
            }
            __syncthreads();
#pragma unroll 4
            for (int kt = 0; kt < 32; kt++) {
                bh8 a   = *(const bh8*)(cs + abase + (((kt * 4 + quad) ^ asw) << 3));
                bh8 bfr = *(const bh8*)(wfp + (size_t)kt * 512);
                bh8 bir = *(const bh8*)(wip + (size_t)kt * 512);
                accF = __builtin_amdgcn_mfma_f32_16x16x32_bf16(a, bfr, accF, 0, 0, 0);
                accI = __builtin_amdgcn_mfma_f32_16x16x32_bf16(a, bir, accI, 0, 0, 0);
            }
        }

        // epilogue: C/D layout col=lane&15, row=quad*4+reg; pack 2 cols/dword, plain store
        // (L1 is write-through -> lands in this XCD's L2; readers are same-XCD only)
#pragma unroll
        for (int r = 0; r < 4; r++) {
            float f = sigf(ffv[r] + accF[r]);
            float i = sigf(iiv[r] + accI[r]);
            float cn = ggv[r] * i + cn_keep[r] * f;
            cn_keep[r] = cn;
            int b = row0 + msub * 16 + quad * 4 + r;
            unsigned us = bf16r(cn);
            unsigned ot = (unsigned)__shfl_xor((int)us, 1);
            if (s < SEQ - 1 && (lane & 1) == 0)
                *(unsigned*)(nxt16 + (size_t)b * H + hcol) = us | (ot << 16);
        }

        if (s < SEQ - 1) {
            asm volatile("s_waitcnt vmcnt(0)" ::: "memory");  // our c stores are in L2
            __syncthreads();                                   // whole WG done
            if (tid == 0) {
                // arrive: workgroup-scope RMW executes at XCD L2 (no sc1)
                __hip_atomic_fetch_add(barp, 1, __ATOMIC_RELAXED,
                                       __HIP_MEMORY_SCOPE_WORKGROUP);
                const int target = 32 * (s + 1);
                int guard = 0;
                while (load_sc0(barp) < target) {
                    if (++guard > (1 << 16)) break;   // desync bailout (debug)
                }
            }
            __syncthreads();
        }
    }

    // o-gate: c_511 still staged in LDS
    f4 accO = {0.f, 0.f, 0.f, 0.f};
#pragma unroll 4
    for (int kt = 0; kt < 32; kt++) {
        bh8 a   = *(const bh8*)(cs + abase + (((kt * 4 + quad) ^ asw) << 3));
        bh8 bor = *(const bh8*)(wop + (size_t)kt * 512);
        accO = __builtin_amdgcn_mfma_f32_16x16x32_bf16(a, bor, accO, 0, 0, 0);
    }
#pragma unroll
    for (int r = 0; r < 4; r++) {
        int b = row0 + msub * 16 + quad * 4 + r;
        int tok = x[b * SEQ + (SEQ - 1)];
        float o = sigf(OO[tok * H + hcol] + accO[r]);
        hb[(size_t)b * H + hcol] = tanhf(cn_keep[r]) * o;
    }
}

// ---------------- p = h @ Wph.T + bp ; out = log_softmax(p) -------------------------------
__global__ __launch_bounds__(128) void out_kernel(
    const float* __restrict__ hbuf, const float* __restrict__ Wph,
    const float* __restrict__ bp, float* __restrict__ out)
{
    const int b = blockIdx.x;
    const int j = threadIdx.x;
    __shared__ float hs[H];
    for (int t = j; t < H; t += 128) hs[t] = hbuf[(size_t)b * H + t];
    __syncthreads();
    const float4* w4 = (const float4*)(Wph + (size_t)j * H);
    const float4* h4 = (const float4*)hs;
    float acc = bp[j];
#pragma unroll 4
    for (int k = 0; k < H / 4; k++) {
        float4 a = w4[k], v = h4[k];
        acc += a.x * v.x + a.y * v.y + a.z * v.z + a.w * v.w;
    }
    __shared__ float red[128];
    red[j] = acc; __syncthreads();
    for (int off = 64; off > 0; off >>= 1) { if (j < off) red[j] = fmaxf(red[j], red[j + off]); __syncthreads(); }
    float m = red[0]; __syncthreads();
    red[j] = __expf(acc - m); __syncthreads();
    for (int off = 64; off > 0; off >>= 1) { if (j < off) red[j] += red[j + off]; __syncthreads(); }
    float lse = m + __logf(red[0]);
    out[(size_t)b * NC + j] = acc - lse;
}

extern "C" void kernel_launch(void* const* d_in, const int* in_sizes, int n_in,
                              void* d_out, int out_size, void* d_ws, size_t ws_size,
                              hipStream_t stream)
{
    const int*   x   = (const int*)d_in[0];
    const float* emb = (const float*)d_in[1];
    const float* Wcx = (const float*)d_in[2];
    const float* bc  = (const float*)d_in[3];
    const float* Wix = (const float*)d_in[4];
    const float* Wih = (const float*)d_in[5];
    const float* bi  = (const float*)d_in[6];
    const float* Wfx = (const float*)d_in[7];
    const float* Wfh = (const float*)d_in[8];
    const float* bf  = (const float*)d_in[9];
    const float* Wox = (const float*)d_in[10];
    const float* Woh = (const float*)d_in[11];
    const float* bo  = (const float*)d_in[12];
    const float* Wph = (const float*)d_in[13];
    const float* bp  = (const float*)d_in[14];
    float* out = (float*)d_out;

    char* wsb = (char*)d_ws;
    float* FF = (float*)(wsb + 0);                         // 512 KB
    float* II = (float*)(wsb + (512 << 10));
    float* OO = (float*)(wsb + (1024 << 10));
    float* G  = (float*)(wsb + (1536 << 10));
    float* hb = (float*)(wsb + (2048 << 10));              // 1 MB
    int*   arr = (int*)(wsb + (3072 << 10));               // 8 groups x 128 B
    int*   cnt = (int*)(wsb + (3072 << 10) + 1024);        // 8 groups x 128 B
    unsigned short* Wf_sw = (unsigned short*)(wsb + (4096 << 10));   // 2 MB each
    unsigned short* Wi_sw = (unsigned short*)(wsb + (6144 << 10));
    unsigned short* Wo_sw = (unsigned short*)(wsb + (8192 << 10));
    unsigned short* c16a  = (unsigned short*)(wsb + (10240 << 10));  // 512 KB each
    unsigned short* c16b  = (unsigned short*)(wsb + (10752 << 10));

    hipMemsetAsync(arr, 0, 2048, stream);   // barrier counters + slot counters

    tables_kernel<<<dim3(NC, 4), 256, 0, stream>>>(emb, Wcx, bc, Wix, bi, Wfx, bf, Wox, bo,
                                                   FF, II, OO, G);
    swz_kernel<<<512, 256, 0, stream>>>(Wfh, Wf_sw);
    swz_kernel<<<512, 256, 0, stream>>>(Wih, Wi_sw);
    swz_kernel<<<512, 256, 0, stream>>>(Woh, Wo_sw);

    persist_kernel<<<NBLK, 256, 0, stream>>>(Wf_sw, Wi_sw, Wo_sw, FF, II, OO, G, x,
                                             c16a, c16b, hb, cnt, arr);

    out_kernel<<<B, 128, 0, stream>>>(hb, Wph, bp, out);
}

// Round 5
// 4963.169 us; speedup vs baseline: 524.6874x; 524.6874x over previous
//
#include <hip/hip_runtime.h>

#define SEQ  512
#define IDIM 256
#define H    1024
#define NC   128
#define B    256
#define NBLK 256

typedef __attribute__((ext_vector_type(8))) short bh8;
typedef __attribute__((ext_vector_type(4))) float f4;
typedef __attribute__((ext_vector_type(4))) int i4;

__device__ __forceinline__ float sigf(float x) { return 1.0f / (1.0f + __expf(-x)); }

__device__ __forceinline__ unsigned short bf16r(float v) {
    unsigned u = __builtin_bit_cast(unsigned, v);
    u += 0x7fffu + ((u >> 16) & 1u);
    return (unsigned short)(u >> 16);
}

// ---------------- token tables: FF/II/OO = emb@W*x.T + b*, G = sigmoid(emb@Wcx.T + bc) ----
__global__ __launch_bounds__(256) void tables_kernel(
    const float* __restrict__ emb,
    const float* __restrict__ Wcx, const float* __restrict__ bc,
    const float* __restrict__ Wix, const float* __restrict__ bi,
    const float* __restrict__ Wfx, const float* __restrict__ bf,
    const float* __restrict__ Wox, const float* __restrict__ bo,
    float* __restrict__ FF, float* __restrict__ II,
    float* __restrict__ OO, float* __restrict__ G)
{
    const int k = blockIdx.x;
    const int h = blockIdx.y * 256 + threadIdx.x;
    __shared__ float e[IDIM];
    e[threadIdx.x] = emb[k * IDIM + threadIdx.x];
    __syncthreads();
    const float4* e4  = (const float4*)e;
    const float4* wf4 = (const float4*)(Wfx + (size_t)h * IDIM);
    const float4* wi4 = (const float4*)(Wix + (size_t)h * IDIM);
    const float4* wo4 = (const float4*)(Wox + (size_t)h * IDIM);
    const float4* wc4 = (const float4*)(Wcx + (size_t)h * IDIM);
    float aF = 0.f, aI = 0.f, aO = 0.f, aC = 0.f;
#pragma unroll 4
    for (int i = 0; i < IDIM / 4; i++) {
        float4 ev = e4[i];
        float4 a = wf4[i]; aF += ev.x * a.x + ev.y * a.y + ev.z * a.z + ev.w * a.w;
        float4 b = wi4[i]; aI += ev.x * b.x + ev.y * b.y + ev.z * b.z + ev.w * b.w;
        float4 c = wo4[i]; aO += ev.x * c.x + ev.y * c.y + ev.z * c.z + ev.w * c.w;
        float4 d = wc4[i]; aC += ev.x * d.x + ev.y * d.y + ev.z * d.z + ev.w * d.w;
    }
    const int o = k * H + h;
    FF[o] = aF + bf[h];
    II[o] = aI + bi[h];
    OO[o] = aO + bo[h];
    G[o]  = sigf(aC + bc[h]);
}

// ---------------- weight fp32 -> bf16 swizzled for MFMA B-fragments -----------------------
__global__ __launch_bounds__(256) void swz_kernel(const float* __restrict__ W,
                                                  unsigned short* __restrict__ D)
{
    int g = blockIdx.x * 256 + threadIdx.x;     // 0..131071
    int h  = g >> 7;
    int kc = (g & 127) << 3;
    const float4* s = (const float4*)(W + (size_t)h * H + kc);
    float4 a = s[0], b = s[1];
    unsigned short tmp[8] = { bf16r(a.x), bf16r(a.y), bf16r(a.z), bf16r(a.w),
                              bf16r(b.x), bf16r(b.y), bf16r(b.z), bf16r(b.w) };
    int nb = h >> 4, kb = kc >> 5, quad = (kc >> 3) & 3;
    int lane = (h & 15) + (quad << 4);
    bh8 v;
#pragma unroll
    for (int j = 0; j < 8; j++) v[j] = (short)tmp[j];
    *(bh8*)(D + (size_t)((nb * 32 + kb) * 512 + lane * 8)) = v;
}

// ---------------- persistent recurrence kernel, LLC exchange, pipelined -------------------
__global__ __launch_bounds__(256, 1) void persist_kernel(
    const unsigned short* __restrict__ Wf, const unsigned short* __restrict__ Wi,
    const unsigned short* __restrict__ Wo,
    const float* __restrict__ FF, const float* __restrict__ II,
    const float* __restrict__ OO, const float* __restrict__ G,
    const int* __restrict__ x,
    unsigned short* c16a, unsigned short* c16b,
    float* __restrict__ hb, int* flags)
{
    const int blk = blockIdx.x;
    const int rt = blk >> 5;            // row-tile 0..7  (32 batch rows)
    const int nt = blk & 31;            // col-tile 0..31 (32 h cols)
    const int tid  = threadIdx.x;
    const int wave = tid >> 6;
    const int lane = tid & 63;
    const int msub = wave & 1, nsub = wave >> 1;
    const int l15 = lane & 15, quad = lane >> 4;

    __shared__ unsigned short cs[32 * 1024];   // 64 KB, XOR-swizzled 16B granules

    const int row0 = rt * 32;
    const int arow = msub * 16 + l15;
    const int abase = arow * 1024;
    const int asw = arow & 7;
    const int hcol = nt * 32 + nsub * 16 + l15;
    const int nb = nt * 2 + nsub;

    const unsigned short* wfp = Wf + (size_t)nb * 32 * 512 + (size_t)lane * 8;
    const unsigned short* wip = Wi + (size_t)nb * 32 * 512 + (size_t)lane * 8;
    const unsigned short* wop = Wo + (size_t)nb * 32 * 512 + (size_t)lane * 8;

    float cn_keep[4] = {0.f, 0.f, 0.f, 0.f};   // fp32 cell state in registers

    for (int s = 0; s < SEQ; s++) {
        const unsigned short* cur16 = (s & 1) ? c16b : c16a;
        unsigned short*       nxt16 = (s & 1) ? c16a : c16b;

        // token-table prefetch (read-only; overlaps with staging latency)
        float ffv[4], iiv[4], ggv[4];
#pragma unroll
        for (int r = 0; r < 4; r++) {
            int b = row0 + msub * 16 + quad * 4 + r;
            int tok = x[b * SEQ + s];
            ffv[r] = FF[tok * H + hcol];
            iiv[r] = II[tok * H + hcol];
            ggv[r] = G[tok * H + hcol];
        }

        f4 accF = {0.f, 0.f, 0.f, 0.f}, accI = {0.f, 0.f, 0.f, 0.f};
        if (s > 0) {
            // stage 32 rows x 2 KB bf16 of c from LLC: 16 pipelined sc0 sc1 16B loads/lane,
            // ONE waitcnt, then LDS writes. (sc0 sc1 = bypass L1+L2, read coherence point —
            // matches the sc0 sc1 write-through stores below; L2 is NOT a sync domain.)
            i4 tmp[16];
#pragma unroll
            for (int i = 0; i < 16; i++) {
                int chunk = i * 256 + tid;
                int row = chunk >> 7, g = chunk & 127;
                const i4* p = (const i4*)(cur16 + (size_t)(row0 + row) * H + g * 8);
                asm volatile("global_load_dwordx4 %0, %1, off sc0 sc1"
                             : "=v"(tmp[i]) : "v"(p));
            }
            asm volatile("s_waitcnt vmcnt(0)" ::: "memory");
#pragma unroll
            for (int i = 0; i < 16; i++) {
                int chunk = i * 256 + tid;
                int row = chunk >> 7, g = chunk & 127;
                *(i4*)(cs + row * 1024 + ((g ^ (row & 7)) << 3)) = tmp[i];
            }
            __syncthreads();
#pragma unroll 4
            for (int kt = 0; kt < 32; kt++) {
                bh8 a   = *(const bh8*)(cs + abase + (((kt * 4 + quad) ^ asw) << 3));
                bh8 bfr = *(const bh8*)(wfp + (size_t)kt * 512);
                bh8 bir = *(const bh8*)(wip + (size_t)kt * 512);
                accF = __builtin_amdgcn_mfma_f32_16x16x32_bf16(a, bfr, accF, 0, 0, 0);
                accI = __builtin_amdgcn_mfma_f32_16x16x32_bf16(a, bir, accI, 0, 0, 0);
            }
        }

        // epilogue: C/D layout col=lane&15, row=quad*4+reg; pack 2 cols/dword,
        // write-through to LLC (sc0 sc1) via agent-scope relaxed store
#pragma unroll
        for (int r = 0; r < 4; r++) {
            float f = sigf(ffv[r] + accF[r]);
            float i = sigf(iiv[r] + accI[r]);
            float cn = ggv[r] * i + cn_keep[r] * f;
            cn_keep[r] = cn;
            int b = row0 + msub * 16 + quad * 4 + r;
            unsigned us = bf16r(cn);
            unsigned ot = (unsigned)__shfl_xor((int)us, 1);
            if (s < SEQ - 1 && (lane & 1) == 0)
                __hip_atomic_store((unsigned*)(nxt16 + (size_t)b * H + hcol), us | (ot << 16),
                                   __ATOMIC_RELAXED, __HIP_MEMORY_SCOPE_AGENT);
        }

        if (s < SEQ - 1) {
            // barrier: per-WG flag (no RMW contention), polls batched in one asm block.
            // __syncthreads drains each wave's vmcnt -> all c stores completed at LLC
            // BEFORE the flag store issues.
            __syncthreads();
            if (tid < 64) {
                if (tid == 0) {
                    int v = s + 1;
                    asm volatile("global_store_dword %0, %1, off sc0 sc1"
                                 :: "v"(&flags[blk]), "v"(v) : "memory");
                }
                const int target = s + 1;
                const int* p0 = &flags[tid];
                const int* p1 = &flags[tid + 64];
                const int* p2 = &flags[tid + 128];
                const int* p3 = &flags[tid + 192];
                int guard = 0;
                for (;;) {
                    int f0, f1, f2, f3;
                    asm volatile(
                        "global_load_dword %0, %4, off sc0 sc1\n\t"
                        "global_load_dword %1, %5, off sc0 sc1\n\t"
                        "global_load_dword %2, %6, off sc0 sc1\n\t"
                        "global_load_dword %3, %7, off sc0 sc1\n\t"
                        "s_waitcnt vmcnt(0)"
                        : "=&v"(f0), "=&v"(f1), "=&v"(f2), "=&v"(f3)
                        : "v"(p0), "v"(p1), "v"(p2), "v"(p3)
                        : "memory");
                    bool ok = (f0 >= target) && (f1 >= target) && (f2 >= target) && (f3 >= target);
                    if (__all(ok)) break;
                    if (++guard > (1 << 20)) break;   // hang bailout (debug)
                }
            }
            __syncthreads();
        }
    }

    // o-gate: c_511 still staged in LDS
    f4 accO = {0.f, 0.f, 0.f, 0.f};
#pragma unroll 4
    for (int kt = 0; kt < 32; kt++) {
        bh8 a   = *(const bh8*)(cs + abase + (((kt * 4 + quad) ^ asw) << 3));
        bh8 bor = *(const bh8*)(wop + (size_t)kt * 512);
        accO = __builtin_amdgcn_mfma_f32_16x16x32_bf16(a, bor, accO, 0, 0, 0);
    }
#pragma unroll
    for (int r = 0; r < 4; r++) {
        int b = row0 + msub * 16 + quad * 4 + r;
        int tok = x[b * SEQ + (SEQ - 1)];
        float o = sigf(OO[tok * H + hcol] + accO[r]);
        hb[(size_t)b * H + hcol] = tanhf(cn_keep[r]) * o;
    }
}

// ---------------- p = h @ Wph.T + bp ; out = log_softmax(p) -------------------------------
__global__ __launch_bounds__(128) void out_kernel(
    const float* __restrict__ hbuf, const float* __restrict__ Wph,
    const float* __restrict__ bp, float* __restrict__ out)
{
    const int b = blockIdx.x;
    const int j = threadIdx.x;
    __shared__ float hs[H];
    for (int t = j; t < H; t += 128) hs[t] = hbuf[(size_t)b * H + t];
    __syncthreads();
    const float4* w4 = (const float4*)(Wph + (size_t)j * H);
    const float4* h4 = (const float4*)hs;
    float acc = bp[j];
#pragma unroll 4
    for (int k = 0; k < H / 4; k++) {
        float4 a = w4[k], v = h4[k];
        acc += a.x * v.x + a.y * v.y + a.z * v.z + a.w * v.w;
    }
    __shared__ float red[128];
    red[j] = acc; __syncthreads();
    for (int off = 64; off > 0; off >>= 1) { if (j < off) red[j] = fmaxf(red[j], red[j + off]); __syncthreads(); }
    float m = red[0]; __syncthreads();
    red[j] = __expf(acc - m); __syncthreads();
    for (int off = 64; off > 0; off >>= 1) { if (j < off) red[j] += red[j + off]; __syncthreads(); }
    float lse = m + __logf(red[0]);
    out[(size_t)b * NC + j] = acc - lse;
}

extern "C" void kernel_launch(void* const* d_in, const int* in_sizes, int n_in,
                              void* d_out, int out_size, void* d_ws, size_t ws_size,
                              hipStream_t stream)
{
    const int*   x   = (const int*)d_in[0];
    const float* emb = (const float*)d_in[1];
    const float* Wcx = (const float*)d_in[2];
    const float* bc  = (const float*)d_in[3];
    const float* Wix = (const float*)d_in[4];
    const float* Wih = (const float*)d_in[5];
    const float* bi  = (const float*)d_in[6];
    const float* Wfx = (const float*)d_in[7];
    const float* Wfh = (const float*)d_in[8];
    const float* bf  = (const float*)d_in[9];
    const float* Wox = (const float*)d_in[10];
    const float* Woh = (const float*)d_in[11];
    const float* bo  = (const float*)d_in[12];
    const float* Wph = (const float*)d_in[13];
    const float* bp  = (const float*)d_in[14];
    float* out = (float*)d_out;

    char* wsb = (char*)d_ws;
    float* FF = (float*)(wsb + 0);                         // 512 KB
    float* II = (float*)(wsb + (512 << 10));
    float* OO = (float*)(wsb + (1024 << 10));
    float* G  = (float*)(wsb + (1536 << 10));
    float* hb = (float*)(wsb + (2048 << 10));              // 1 MB
    int*   flags = (int*)(wsb + (3072 << 10));             // 1 KB
    unsigned short* Wf_sw = (unsigned short*)(wsb + (4096 << 10));   // 2 MB each
    unsigned short* Wi_sw = (unsigned short*)(wsb + (6144 << 10));
    unsigned short* Wo_sw = (unsigned short*)(wsb + (8192 << 10));
    unsigned short* c16a  = (unsigned short*)(wsb + (10240 << 10));  // 512 KB each
    unsigned short* c16b  = (unsigned short*)(wsb + (10752 << 10));

    hipMemsetAsync(flags, 0, NBLK * sizeof(int), stream);   // barrier flags = 0

    tables_kernel<<<dim3(NC, 4), 256, 0, stream>>>(emb, Wcx, bc, Wix, bi, Wfx, bf, Wox, bo,
                                                   FF, II, OO, G);
    swz_kernel<<<512, 256, 0, stream>>>(Wfh, Wf_sw);
    swz_kernel<<<512, 256, 0, stream>>>(Wih, Wi_sw);
    swz_kernel<<<512, 256, 0, stream>>>(Woh, Wo_sw);

    persist_kernel<<<NBLK, 256, 0, stream>>>(Wf_sw, Wi_sw, Wo_sw, FF, II, OO, G, x,
                                             c16a, c16b, hb, flags);

    out_kernel<<<B, 128, 0, stream>>>(hb, Wph, bp, out);
}

// Round 6
// 2757.468 us; speedup vs baseline: 944.3851x; 1.7999x over previous
//
#include <hip/hip_runtime.h>

#define SEQ  512
#define IDIM 256
#define H    1024
#define NC   128
#define B    256
#define NBLK 256

typedef __attribute__((ext_vector_type(8))) short bh8;
typedef __attribute__((ext_vector_type(4))) float f4;
typedef __attribute__((ext_vector_type(4))) int i4;

__device__ __forceinline__ float sigf(float x) { return 1.0f / (1.0f + __expf(-x)); }

__device__ __forceinline__ unsigned short bf16r(float v) {
    unsigned u = __builtin_bit_cast(unsigned, v);
    u += 0x7fffu + ((u >> 16) & 1u);
    return (unsigned short)(u >> 16);
}

// ---------------- token tables: FF/II/OO = emb@W*x.T + b*, G = sigmoid(emb@Wcx.T + bc) ----
__global__ __launch_bounds__(256) void tables_kernel(
    const float* __restrict__ emb,
    const float* __restrict__ Wcx, const float* __restrict__ bc,
    const float* __restrict__ Wix, const float* __restrict__ bi,
    const float* __restrict__ Wfx, const float* __restrict__ bf,
    const float* __restrict__ Wox, const float* __restrict__ bo,
    float* __restrict__ FF, float* __restrict__ II,
    float* __restrict__ OO, float* __restrict__ G)
{
    const int k = blockIdx.x;
    const int h = blockIdx.y * 256 + threadIdx.x;
    __shared__ float e[IDIM];
    e[threadIdx.x] = emb[k * IDIM + threadIdx.x];
    __syncthreads();
    const float4* e4  = (const float4*)e;
    const float4* wf4 = (const float4*)(Wfx + (size_t)h * IDIM);
    const float4* wi4 = (const float4*)(Wix + (size_t)h * IDIM);
    const float4* wo4 = (const float4*)(Wox + (size_t)h * IDIM);
    const float4* wc4 = (const float4*)(Wcx + (size_t)h * IDIM);
    float aF = 0.f, aI = 0.f, aO = 0.f, aC = 0.f;
#pragma unroll 4
    for (int i = 0; i < IDIM / 4; i++) {
        float4 ev = e4[i];
        float4 a = wf4[i]; aF += ev.x * a.x + ev.y * a.y + ev.z * a.z + ev.w * a.w;
        float4 b = wi4[i]; aI += ev.x * b.x + ev.y * b.y + ev.z * b.z + ev.w * b.w;
        float4 c = wo4[i]; aO += ev.x * c.x + ev.y * c.y + ev.z * c.z + ev.w * c.w;
        float4 d = wc4[i]; aC += ev.x * d.x + ev.y * d.y + ev.z * d.z + ev.w * d.w;
    }
    const int o = k * H + h;
    FF[o] = aF + bf[h];
    II[o] = aI + bi[h];
    OO[o] = aO + bo[h];
    G[o]  = sigf(aC + bc[h]);
}

// ---------------- weight fp32 -> bf16 swizzled for MFMA B-fragments -----------------------
__global__ __launch_bounds__(256) void swz_kernel(const float* __restrict__ W,
                                                  unsigned short* __restrict__ D)
{
    int g = blockIdx.x * 256 + threadIdx.x;     // 0..131071
    int h  = g >> 7;
    int kc = (g & 127) << 3;
    const float4* s = (const float4*)(W + (size_t)h * H + kc);
    float4 a = s[0], b = s[1];
    unsigned short tmp[8] = { bf16r(a.x), bf16r(a.y), bf16r(a.z), bf16r(a.w),
                              bf16r(b.x), bf16r(b.y), bf16r(b.z), bf16r(b.w) };
    int nb = h >> 4, kb = kc >> 5, quad = (kc >> 3) & 3;
    int lane = (h & 15) + (quad << 4);
    bh8 v;
#pragma unroll
    for (int j = 0; j < 8; j++) v[j] = (short)tmp[j];
    *(bh8*)(D + (size_t)((nb * 32 + kb) * 512 + lane * 8)) = v;
}

// ---------------- persistent recurrence kernel: weights in VGPRs, group-local barrier -----
__global__ __launch_bounds__(256, 1) void persist_kernel(
    const unsigned short* __restrict__ Wf, const unsigned short* __restrict__ Wi,
    const unsigned short* __restrict__ Wo,
    const float* __restrict__ FF, const float* __restrict__ II,
    const float* __restrict__ OO, const float* __restrict__ G,
    const int* __restrict__ x,
    unsigned short* c16a, unsigned short* c16b,
    float* __restrict__ hb, int* flags)
{
    const int blk = blockIdx.x;
    const int rt = blk >> 5;            // row-tile 0..7  (32 batch rows) — groups are independent
    const int nt = blk & 31;            // col-tile 0..31 within group
    const int tid  = threadIdx.x;
    const int wave = tid >> 6;
    const int lane = tid & 63;
    const int msub = wave & 1, nsub = wave >> 1;
    const int l15 = lane & 15, quad = lane >> 4;

    __shared__ unsigned short cs[32 * 1024];   // 64 KB, XOR-swizzled 16B granules

    const int row0 = rt * 32;
    const int arow = msub * 16 + l15;
    const int abase = arow * 1024;
    const int asw = arow & 7;
    const int hcol = nt * 32 + nsub * 16 + l15;
    const int nb = nt * 2 + nsub;

    const unsigned short* wfp = Wf + (size_t)nb * 32 * 512 + (size_t)lane * 8;
    const unsigned short* wip = Wi + (size_t)nb * 32 * 512 + (size_t)lane * 8;
    const unsigned short* wop = Wo + (size_t)nb * 32 * 512 + (size_t)lane * 8;

    // F/I weight fragments are loop-invariant: hold all 32 kt frags of both gates in VGPRs
    // (1 KB/lane = 256 VGPRs; occupancy is LDS-bound at 1 wave/SIMD, so budget is ~512)
    bh8 wf_r[32], wi_r[32];
#pragma unroll
    for (int kt = 0; kt < 32; kt++) {
        wf_r[kt] = *(const bh8*)(wfp + (size_t)kt * 512);
        wi_r[kt] = *(const bh8*)(wip + (size_t)kt * 512);
    }

    float cn_keep[4] = {0.f, 0.f, 0.f, 0.f};   // fp32 cell state in registers

    for (int s = 0; s < SEQ; s++) {
        const unsigned short* cur16 = (s & 1) ? c16b : c16a;
        unsigned short*       nxt16 = (s & 1) ? c16a : c16b;

        // token-table prefetch (read-only; overlaps staging latency)
        float ffv[4], iiv[4], ggv[4];
#pragma unroll
        for (int r = 0; r < 4; r++) {
            int b = row0 + msub * 16 + quad * 4 + r;
            int tok = x[b * SEQ + s];
            ffv[r] = FF[tok * H + hcol];
            iiv[r] = II[tok * H + hcol];
            ggv[r] = G[tok * H + hcol];
        }

        f4 accF = {0.f, 0.f, 0.f, 0.f}, accI = {0.f, 0.f, 0.f, 0.f};
        if (s > 0) {
            // stage 32 rows x 2 KB bf16 of c from LLC: 16 pipelined sc0 sc1 loads/lane,
            // ONE waitcnt, then LDS writes (LLC is the only legal sync domain — r4 lesson)
            i4 tmp[16];
#pragma unroll
            for (int i = 0; i < 16; i++) {
                int chunk = i * 256 + tid;
                int row = chunk >> 7, g = chunk & 127;
                const i4* p = (const i4*)(cur16 + (size_t)(row0 + row) * H + g * 8);
                asm volatile("global_load_dwordx4 %0, %1, off sc0 sc1"
                             : "=v"(tmp[i]) : "v"(p));
            }
            asm volatile("s_waitcnt vmcnt(0)" ::: "memory");
#pragma unroll
            for (int i = 0; i < 16; i++) {
                int chunk = i * 256 + tid;
                int row = chunk >> 7, g = chunk & 127;
                *(i4*)(cs + row * 1024 + ((g ^ (row & 7)) << 3)) = tmp[i];
            }
            __syncthreads();
#pragma unroll
            for (int kt = 0; kt < 32; kt++) {
                bh8 a = *(const bh8*)(cs + abase + (((kt * 4 + quad) ^ asw) << 3));
                accF = __builtin_amdgcn_mfma_f32_16x16x32_bf16(a, wf_r[kt], accF, 0, 0, 0);
                accI = __builtin_amdgcn_mfma_f32_16x16x32_bf16(a, wi_r[kt], accI, 0, 0, 0);
            }
        }

        // epilogue: C/D col=lane&15, row=quad*4+reg; pack 2 cols/dword, write-through to LLC
#pragma unroll
        for (int r = 0; r < 4; r++) {
            float f = sigf(ffv[r] + accF[r]);
            float i = sigf(iiv[r] + accI[r]);
            float cn = ggv[r] * i + cn_keep[r] * f;
            cn_keep[r] = cn;
            int b = row0 + msub * 16 + quad * 4 + r;
            unsigned us = bf16r(cn);
            unsigned ot = (unsigned)__shfl_xor((int)us, 1);
            if (s < SEQ - 1 && (lane & 1) == 0)
                __hip_atomic_store((unsigned*)(nxt16 + (size_t)b * H + hcol), us | (ot << 16),
                                   __ATOMIC_RELAXED, __HIP_MEMORY_SCOPE_AGENT);
        }

        if (s < SEQ - 1) {
            // GROUP-LOCAL barrier: only the 32 WGs sharing rt exchange data.
            // __syncthreads drains every wave's vmcnt -> c stores visible at LLC first.
            __syncthreads();
            if (wave == 0) {
                if (lane == 0) {
                    int v = s + 1;
                    asm volatile("global_store_dword %0, %1, off sc0 sc1"
                                 :: "v"(&flags[blk]), "v"(v) : "memory");
                }
                const int target = s + 1;
                const int* pf = &flags[rt * 32 + (lane & 31)];
                int guard = 0;
                for (;;) {
                    int fv;
                    asm volatile("global_load_dword %0, %1, off sc0 sc1\n\ts_waitcnt vmcnt(0)"
                                 : "=v"(fv) : "v"(pf) : "memory");
                    if (__all(fv >= target)) break;
                    if (++guard > (1 << 20)) break;   // hang bailout (debug)
                }
            }
            __syncthreads();
        }
    }

    // o-gate: c_511 still staged in LDS; Wo streamed from L2 (used once)
    f4 accO = {0.f, 0.f, 0.f, 0.f};
#pragma unroll 4
    for (int kt = 0; kt < 32; kt++) {
        bh8 a   = *(const bh8*)(cs + abase + (((kt * 4 + quad) ^ asw) << 3));
        bh8 bor = *(const bh8*)(wop + (size_t)kt * 512);
        accO = __builtin_amdgcn_mfma_f32_16x16x32_bf16(a, bor, accO, 0, 0, 0);
    }
#pragma unroll
    for (int r = 0; r < 4; r++) {
        int b = row0 + msub * 16 + quad * 4 + r;
        int tok = x[b * SEQ + (SEQ - 1)];
        float o = sigf(OO[tok * H + hcol] + accO[r]);
        hb[(size_t)b * H + hcol] = tanhf(cn_keep[r]) * o;
    }
}

// ---------------- p = h @ Wph.T + bp ; out = log_softmax(p) -------------------------------
__global__ __launch_bounds__(128) void out_kernel(
    const float* __restrict__ hbuf, const float* __restrict__ Wph,
    const float* __restrict__ bp, float* __restrict__ out)
{
    const int b = blockIdx.x;
    const int j = threadIdx.x;
    __shared__ float hs[H];
    for (int t = j; t < H; t += 128) hs[t] = hbuf[(size_t)b * H + t];
    __syncthreads();
    const float4* w4 = (const float4*)(Wph + (size_t)j * H);
    const float4* h4 = (const float4*)hs;
    float acc = bp[j];
#pragma unroll 4
    for (int k = 0; k < H / 4; k++) {
        float4 a = w4[k], v = h4[k];
        acc += a.x * v.x + a.y * v.y + a.z * v.z + a.w * v.w;
    }
    __shared__ float red[128];
    red[j] = acc; __syncthreads();
    for (int off = 64; off > 0; off >>= 1) { if (j < off) red[j] = fmaxf(red[j], red[j + off]); __syncthreads(); }
    float m = red[0]; __syncthreads();
    red[j] = __expf(acc - m); __syncthreads();
    for (int off = 64; off > 0; off >>= 1) { if (j < off) red[j] += red[j + off]; __syncthreads(); }
    float lse = m + __logf(red[0]);
    out[(size_t)b * NC + j] = acc - lse;
}

extern "C" void kernel_launch(void* const* d_in, const int* in_sizes, int n_in,
                              void* d_out, int out_size, void* d_ws, size_t ws_size,
                              hipStream_t stream)
{
    const int*   x   = (const int*)d_in[0];
    const float* emb = (const float*)d_in[1];
    const float* Wcx = (const float*)d_in[2];
    const float* bc  = (const float*)d_in[3];
    const float* Wix = (const float*)d_in[4];
    const float* Wih = (const float*)d_in[5];
    const float* bi  = (const float*)d_in[6];
    const float* Wfx = (const float*)d_in[7];
    const float* Wfh = (const float*)d_in[8];
    const float* bf  = (const float*)d_in[9];
    const float* Wox = (const float*)d_in[10];
    const float* Woh = (const float*)d_in[11];
    const float* bo  = (const float*)d_in[12];
    const float* Wph = (const float*)d_in[13];
    const float* bp  = (const float*)d_in[14];
    float* out = (float*)d_out;

    char* wsb = (char*)d_ws;
    float* FF = (float*)(wsb + 0);                         // 512 KB
    float* II = (float*)(wsb + (512 << 10));
    float* OO = (float*)(wsb + (1024 << 10));
    float* G  = (float*)(wsb + (1536 << 10));
    float* hb = (float*)(wsb + (2048 << 10));              // 1 MB
    int*   flags = (int*)(wsb + (3072 << 10));             // 1 KB
    unsigned short* Wf_sw = (unsigned short*)(wsb + (4096 << 10));   // 2 MB each
    unsigned short* Wi_sw = (unsigned short*)(wsb + (6144 << 10));
    unsigned short* Wo_sw = (unsigned short*)(wsb + (8192 << 10));
    unsigned short* c16a  = (unsigned short*)(wsb + (10240 << 10));  // 512 KB each
    unsigned short* c16b  = (unsigned short*)(wsb + (10752 << 10));

    hipMemsetAsync(flags, 0, NBLK * sizeof(int), stream);   // barrier flags = 0

    tables_kernel<<<dim3(NC, 4), 256, 0, stream>>>(emb, Wcx, bc, Wix, bi, Wfx, bf, Wox, bo,
                                                   FF, II, OO, G);
    swz_kernel<<<512, 256, 0, stream>>>(Wfh, Wf_sw);
    swz_kernel<<<512, 256, 0, stream>>>(Wih, Wi_sw);
    swz_kernel<<<512, 256, 0, stream>>>(Woh, Wo_sw);

    persist_kernel<<<NBLK, 256, 0, stream>>>(Wf_sw, Wi_sw, Wo_sw, FF, II, OO, G, x,
                                             c16a, c16b, hb, flags);

    out_kernel<<<B, 128, 0, stream>>>(hb, Wph, bp, out);
}